// Round 11
// baseline (256.976 us; speedup 1.0000x reference)
//
#include <hip/hip_runtime.h>
#include <math.h>

#define BATCH 8
#define NPTS 4096
#define CHAN 128
#define KNN 16
#define PTILE 32               // points per block (kernel 1)
#define NGRP 16                // candidate groups per block
#define QCH (NPTS / NGRP)      // 256 candidates per thread (8-bit local idx)
#define EPC 24                 // slow-path survivor buffer capacity

typedef unsigned long long u64;

// Monotone key: ascending u64 == (d2 ascending, idx ascending).
// Ties in d2 break toward lower index == lax.top_k stable order.
__device__ __forceinline__ u64 pack_key(float d2, int idx) {
  unsigned b = __float_as_uint(d2);
  b ^= (unsigned)((int)b >> 31) | 0x80000000u;  // order-preserving fp32 map
  return ((u64)b << 32) | (unsigned)idx;
}

// Reference d2: inner = ((x0*y0 + x1*y1) + x2*y2) fp32 no-fma (numpy einsum
// order); d2 = (sq_n + sq_m) - 2*inner. Bit-exact vs JAX reference.
__device__ __forceinline__ float d2_ref(float4 q, float ppx, float ppy,
                                        float ppz, float psq) {
  float inner = __fadd_rn(__fadd_rn(__fmul_rn(ppx, q.x), __fmul_rn(ppy, q.y)),
                          __fmul_rn(ppz, q.z));
  return __fsub_rn(__fadd_rn(psq, q.w), __fmul_rn(2.0f, inner));
}

// ----- u64 compare-exchange machinery ---------------------------------------
__device__ __forceinline__ void ce_asc(u64& x, u64& y) {
  bool sw = y < x;
  u64 lo = sw ? y : x;
  u64 hi = sw ? x : y;
  x = lo;
  y = hi;
}

// Batcher merge-exchange sort of 16 u64 keys, ascending. 63 CE.
__device__ __forceinline__ void batcher_sort16_u64(u64 a[16]) {
#define CE(i, j) ce_asc(a[i], a[j])
  CE(0, 8); CE(1, 9); CE(2, 10); CE(3, 11);
  CE(4, 12); CE(5, 13); CE(6, 14); CE(7, 15);
  CE(0, 4); CE(1, 5); CE(2, 6); CE(3, 7);
  CE(8, 12); CE(9, 13); CE(10, 14); CE(11, 15);
  CE(4, 8); CE(5, 9); CE(6, 10); CE(7, 11);
  CE(0, 2); CE(1, 3); CE(4, 6); CE(5, 7);
  CE(8, 10); CE(9, 11); CE(12, 14); CE(13, 15);
  CE(2, 8); CE(3, 9); CE(6, 12); CE(7, 13);
  CE(2, 4); CE(3, 5); CE(6, 8); CE(7, 9); CE(10, 12); CE(11, 13);
  CE(0, 1); CE(2, 3); CE(4, 5); CE(6, 7);
  CE(8, 9); CE(10, 11); CE(12, 13); CE(14, 15);
  CE(1, 8); CE(3, 10); CE(5, 12); CE(7, 14);
  CE(1, 4); CE(3, 6); CE(5, 8); CE(7, 10); CE(9, 12); CE(11, 14);
  CE(1, 2); CE(3, 4); CE(5, 6); CE(7, 8); CE(9, 10); CE(11, 12); CE(13, 14);
#undef CE
}

// Bitonic sort of 32 u64 keys, ascending. 240 CE (slow path only).
__device__ __forceinline__ void bitonic_sort32(u64 a[32]) {
#pragma unroll
  for (int k = 2; k <= 32; k <<= 1) {
#pragma unroll
    for (int j = k >> 1; j > 0; j >>= 1) {
#pragma unroll
      for (int i = 0; i < 32; ++i) {
        int l = i ^ j;
        if (l > i) {
          if ((i & k) == 0) ce_asc(a[i], a[l]);
          else              ce_asc(a[l], a[i]);
        }
      }
    }
  }
}

// T, A both sorted ascending. T <- lowest-16 of (T ∪ A), sorted ascending.
__device__ __forceinline__ void merge_keep16(u64 T[16], const u64 A[16]) {
  u64 nt[16];
#pragma unroll
  for (int i = 0; i < 16; ++i) {
    u64 a = A[15 - i];
    nt[i] = (a < T[i]) ? a : T[i];
  }
#pragma unroll
  for (int j = 8; j > 0; j >>= 1) {
#pragma unroll
    for (int i = 0; i < 16; ++i) {
      int l = i ^ j;
      if (l > i) ce_asc(nt[i], nt[l]);
    }
  }
#pragma unroll
  for (int i = 0; i < 16; ++i) T[i] = nt[i];
}

// ----- i32 packed-key machinery (hot phase 1) ------------------------------
// Packed key = (d2bits & ~255) | local_idx (8-bit). Signed-i32 ascending ==
// (trunc(d2), idx) ascending for all d2 >= 0 (negatives sort below all
// positives -> always selected -> exact epilogue fixes internal order).
// CE = v_min_i32 + v_max_i32 = 2 VALU.
__device__ __forceinline__ void ce_i32(int& x, int& y) {
  int lo = (x < y) ? x : y;
  int hi = (x < y) ? y : x;
  x = lo;
  y = hi;
}

// Batcher merge-exchange sort of 16 i32 keys, ascending. 63 CE.
__device__ __forceinline__ void batcher_sort16_i32(int a[16]) {
#define CE(i, j) ce_i32(a[i], a[j])
  CE(0, 8); CE(1, 9); CE(2, 10); CE(3, 11);
  CE(4, 12); CE(5, 13); CE(6, 14); CE(7, 15);
  CE(0, 4); CE(1, 5); CE(2, 6); CE(3, 7);
  CE(8, 12); CE(9, 13); CE(10, 14); CE(11, 15);
  CE(4, 8); CE(5, 9); CE(6, 10); CE(7, 11);
  CE(0, 2); CE(1, 3); CE(4, 6); CE(5, 7);
  CE(8, 10); CE(9, 11); CE(12, 14); CE(13, 15);
  CE(2, 8); CE(3, 9); CE(6, 12); CE(7, 13);
  CE(2, 4); CE(3, 5); CE(6, 8); CE(7, 9); CE(10, 12); CE(11, 13);
  CE(0, 1); CE(2, 3); CE(4, 5); CE(6, 7);
  CE(8, 9); CE(10, 11); CE(12, 13); CE(14, 15);
  CE(1, 8); CE(3, 10); CE(5, 12); CE(7, 14);
  CE(1, 4); CE(3, 6); CE(5, 8); CE(7, 10); CE(9, 12); CE(11, 14);
  CE(1, 2); CE(3, 4); CE(5, 6); CE(7, 8); CE(9, 10); CE(11, 12); CE(13, 14);
#undef CE
}

// T, A sorted ascending (i32). T <- lowest-16 of (T ∪ A). 80 VALU.
__device__ __forceinline__ void merge_keep16_i32(int T[16], const int A[16]) {
  int nt[16];
#pragma unroll
  for (int i = 0; i < 16; ++i) {
    int a = A[15 - i];
    nt[i] = (a < T[i]) ? a : T[i];
  }
#pragma unroll
  for (int j = 8; j > 0; j >>= 1) {
#pragma unroll
    for (int i = 0; i < 16; ++i) {
      int l = i ^ j;
      if (l > i) ce_i32(nt[i], nt[l]);
    }
  }
#pragma unroll
  for (int i = 0; i < 16; ++i) T[i] = nt[i];
}

// ---------------------------------------------------------------------------
// Kernel 1 (fused knn + merge + score): tail analysis (R7-R10) showed the
// ~112us non-knn tail is invariant to tail-kernel structure -> dominated by
// per-kernel launch/dispatch gaps (~18us each), not execution. So: fuse.
// Block = 32 points x 16 groups (512 thr); the whole batch (4096 cands,
// 64 KB) is LDS-staged, each group scans its 256-cand window. The per-thread
// hot loop (16 batches, 8-bit packed keys, r17 guard, u8 slow scratch) is
// byte-identical to the proven R6-R10 form. After the epilogue, xs is dead
// (barrier) and is REUSED as the 64 KB combine staging buffer for a 4-round
// binary tree merge in [g][j][p] SoA layout (conflict-free, == old mbuf).
// Group 0 then computes the score (neighbors gathered from global x, L2-hot)
// and writes score directly. pkey (16.8 MB round-trip), merge_score kernel,
// and the cnt array all cease to exist.
// grid: BATCH * (NPTS/PTILE) = 1024 blocks; LDS 76 KB -> 2 blocks/CU.
// Exactness: tau superset + exact r17 guard (unchanged); fast path rebuilds
// exact u64 keys; slow path rescans {trunc <= tau}; tree merge is set-union
// of unique keys -> order-invariant -> bit-identical top-16 list; score sum
// in numpy pairwise order (validated round 2).
// ---------------------------------------------------------------------------
__global__ __launch_bounds__(512) void knn_score_kernel(
    const float* __restrict__ x, float* __restrict__ score) {
  const int ntile = blockIdx.x % (NPTS / PTILE);
  const int b = blockIdx.x / (NPTS / PTILE);
  const int p = threadIdx.x & (PTILE - 1);
  const int g = threadIdx.x >> 5;  // group 0..15 (2 groups per wave)
  __shared__ float4 xs[NPTS];                    // 64 KB; reused as stage
  __shared__ unsigned char scratch[512 * EPC];   // 12 KB slow-path

  const float* xb = x + (size_t)b * 3 * NPTS;
  for (int i = threadIdx.x; i < NPTS; i += 512) {
    float px = xb[i];
    float py = xb[NPTS + i];
    float pz = xb[2 * NPTS + i];
    float sq = __fadd_rn(__fadd_rn(__fmul_rn(px, px), __fmul_rn(py, py)),
                         __fmul_rn(pz, pz));
    xs[i] = make_float4(px, py, pz, sq);
  }
  __syncthreads();

  const int n = ntile * PTILE + p;
  float4 pp = xs[n];
  const float ppx = pp.x, ppy = pp.y, ppz = pp.z, psq = pp.w;

  const int cbase = g * QCH;

  // ---- Phase 1: top-16 packed keys + exact 17th (r17) ----
  int T[16];
#pragma unroll
  for (int i = 0; i < 16; ++i) T[i] = 0x7FFFFFFF;  // sentinel > any real key
  int r17 = 0x7FFFFFFF;

#pragma unroll 1
  for (int base = 0; base < QCH; base += 16) {
    int A[16];
#pragma unroll
    for (int t = 0; t < 16; ++t) {
      float4 q = xs[cbase + base + t];
      int bits = __float_as_int(d2_ref(q, ppx, ppy, ppz, psq));
      A[t] = (bits & 0xFFFFFF00) | (base + t);
    }
    batcher_sort16_i32(A);
    // 17th smallest of (T ∪ A), both sorted: min_i max(T[i], A[15-i])
    int u[16];
#pragma unroll
    for (int i = 0; i < 16; ++i) {
      int a = A[15 - i];
      u[i] = (T[i] < a) ? a : T[i];  // max
    }
#pragma unroll
    for (int w = 8; w > 0; w >>= 1) {
#pragma unroll
      for (int i = 0; i < 16; ++i) {
        if (i < w) u[i] = (u[i] < u[i + w]) ? u[i] : u[i + w];  // min
      }
    }
    r17 = (r17 < u[0]) ? r17 : u[0];
    merge_keep16_i32(T, A);
  }

  const int tau = T[15] & 0xFFFFFF00;
  const bool slow = ((r17 & 0xFFFFFF00) == tau);

  // ---- Epilogue: exact u64 top-16 keys for this group's window ----
  u64 K[16];
  if (!slow) {
#pragma unroll
    for (int j = 0; j < 16; ++j) {
      int loc = cbase + (T[j] & 255);
      float4 q = xs[loc];
      float d2 = d2_ref(q, ppx, ppy, ppz, psq);
      K[j] = pack_key(d2, loc);
    }
    batcher_sort16_u64(K);
  } else {
    unsigned char* myb = scratch + (unsigned)threadIdx.x * EPC;
    int cnt = 0;
#pragma unroll 4
    for (int m = 0; m < QCH; ++m) {
      float4 q = xs[cbase + m];
      int tb = __float_as_int(d2_ref(q, ppx, ppy, ppz, psq)) & 0xFFFFFF00;
      if (tb <= tau) {
        myb[cnt < EPC - 1 ? cnt : EPC - 1] = (unsigned char)m;
        ++cnt;
      }
    }
    u64 KK[32];
#pragma unroll
    for (int j = 0; j < EPC; ++j) {
      int loc = cbase + myb[j];  // u8 always < QCH; garbage past cnt masked
      float4 q = xs[loc];
      float d2 = d2_ref(q, ppx, ppy, ppz, psq);
      u64 k = pack_key(d2, loc);
      KK[j] = (j < cnt) ? k : ~0ull;
    }
#pragma unroll
    for (int j = EPC; j < 32; ++j) KK[j] = ~0ull;
    bitonic_sort32(KK);
#pragma unroll
    for (int j = 0; j < 16; ++j) K[j] = KK[j];
  }

  // ---- combine 16 groups: binary tree in LDS (xs reused as staging) ----
  __syncthreads();  // all xs reads (incl. slow-path rescans) complete
  u64* stg = reinterpret_cast<u64*>(xs);  // [g][j][p]: (g*16+j)*PTILE + p
#pragma unroll
  for (int j = 0; j < 16; ++j) stg[(g * 16 + j) * PTILE + p] = K[j];
  __syncthreads();
#pragma unroll 1
  for (int r = 8; r >= 1; r >>= 1) {
    if (g < r) {
      u64 A64[16];
#pragma unroll
      for (int j = 0; j < 16; ++j)
        A64[j] = stg[((g + r) * 16 + j) * PTILE + p];
      merge_keep16(K, A64);
      if (r > 1) {
#pragma unroll
        for (int j = 0; j < 16; ++j) stg[(g * 16 + j) * PTILE + p] = K[j];
      }
    }
    __syncthreads();
  }

  // ---- group 0: score from global x (xs destroyed), numpy pairwise ----
  if (g == 0) {
    float nx[KNN], ny[KNN], nz[KNN];
#pragma unroll
    for (int j = 0; j < KNN; ++j) {
      int idx = (int)(unsigned)K[j];
      nx[j] = xb[idx];
      ny[j] = xb[NPTS + idx];
      nz[j] = xb[2 * NPTS + idx];
    }
    float P[3];
#pragma unroll
    for (int d = 0; d < 3; ++d) {
      const float pc = (d == 0) ? ppx : ((d == 1) ? ppy : ppz);
      float r[8];
#pragma unroll
      for (int j = 0; j < 8; ++j) {
        float c0 = (d == 0) ? nx[j] : ((d == 1) ? ny[j] : nz[j]);
        float c1 = (d == 0) ? nx[j + 8] : ((d == 1) ? ny[j + 8] : nz[j + 8]);
        float e0 = __fsub_rn(c0, pc);
        float e1 = __fsub_rn(c1, pc);
        r[j] = __fadd_rn(__fmul_rn(e0, e0), __fmul_rn(e1, e1));
      }
      float t0 = __fadd_rn(r[0], r[1]);
      float t1 = __fadd_rn(r[2], r[3]);
      float t2 = __fadd_rn(r[4], r[5]);
      float t3 = __fadd_rn(r[6], r[7]);
      P[d] = __fadd_rn(__fadd_rn(t0, t1), __fadd_rn(t2, t3));
    }
    score[(size_t)b * NPTS + n] =
        __fadd_rn(__fadd_rn(P[0], P[1]), P[2]);
  }
}

// ---------------------------------------------------------------------------
// Kernel 2 (fused rank + scatter, atomics-free): block = 128 points x 2
// scan-halves (256 thr). All 4096 scores LDS-staged as float4; each thread
// counts over its 2048-candidate half; halves combined via LDS; h==0 writes
// sel[b][c] = n directly. rank(n) = #{m: s[m]>s[n] or (s[m]==s[n] and m<n)}
// is a total order -> c unique -> collision-free scatter == stable desc
// argsort (validated earlier rounds). No cnt array, no atomics, one launch
// instead of two. grid: BATCH*(NPTS/128) = 256 blocks.
// ---------------------------------------------------------------------------
__global__ __launch_bounds__(256) void rank_scatter_kernel(
    const float* __restrict__ score, int* __restrict__ sel, int npts) {
  const int tile = blockIdx.x % (NPTS / 128);
  const int b = blockIdx.x / (NPTS / 128);
  const int p = threadIdx.x & 127;
  const int h = threadIdx.x >> 7;
  __shared__ float4 sv[NPTS / 4];  // 16 KB
  __shared__ int cpart[128];

  const float* sb = score + (size_t)b * NPTS;
  const float4* sb4 = reinterpret_cast<const float4*>(sb);
  for (int i = threadIdx.x; i < NPTS / 4; i += 256) sv[i] = sb4[i];

  const int n = tile * 128 + p;
  const float sn = sb[n];
  __syncthreads();

  int c = 0;
  const int v0 = h * (NPTS / 8);
#pragma unroll 4
  for (int v = v0; v < v0 + NPTS / 8; ++v) {
    float4 f = sv[v];
    int gm = 4 * v;
    c += (f.x > sn) || (f.x == sn && gm < n);
    c += (f.y > sn) || (f.y == sn && gm + 1 < n);
    c += (f.z > sn) || (f.z == sn && gm + 2 < n);
    c += (f.w > sn) || (f.w == sn && gm + 3 < n);
  }
  if (h == 1) cpart[p] = c;
  __syncthreads();
  if (h == 0) {
    c += cpart[p];
    if (c < npts) sel[(size_t)b * npts + c] = n;
  }
}

// ---------------------------------------------------------------------------
// Kernel 3: gather xyz then features into the concatenated flat output.
// ---------------------------------------------------------------------------
__global__ __launch_bounds__(256) void gather_kernel(
    const float* __restrict__ x, const float* __restrict__ y,
    const int* __restrict__ sel, float* __restrict__ out, int npts,
    int total0, int total) {
  int tid = blockIdx.x * blockDim.x + threadIdx.x;
  if (tid >= total) return;
  if (tid < total0) {
    int j = tid % npts;
    int rest = tid / npts;
    int d = rest % 3;
    int b = rest / 3;
    int src = sel[b * npts + j];
    out[tid] = x[((size_t)b * 3 + d) * NPTS + src];
  } else {
    int t = tid - total0;
    int j = t % npts;
    int rest = t / npts;
    int c = rest % CHAN;
    int b = rest / CHAN;
    int src = sel[b * npts + j];
    out[tid] = y[((size_t)b * CHAN + c) * NPTS + src];
  }
}

extern "C" void kernel_launch(void* const* d_in, const int* in_sizes, int n_in,
                              void* d_out, int out_size, void* d_ws,
                              size_t ws_size, hipStream_t stream) {
  const float* x = (const float*)d_in[0];
  const float* y = (const float*)d_in[1];
  float* out = (float*)d_out;

  const int npts = out_size / (BATCH * (3 + CHAN));

  // workspace layout (pkey and cnt eliminated):
  char* w = (char*)d_ws;
  float* score = (float*)w;                  // B*N f32 = 128 KB
  w += sizeof(float) * (size_t)BATCH * NPTS;
  int* sel = (int*)w;                        // B*npts i32

  knn_score_kernel<<<BATCH * (NPTS / PTILE), 512, 0, stream>>>(x, score);
  rank_scatter_kernel<<<BATCH * (NPTS / 128), 256, 0, stream>>>(score, sel,
                                                                npts);
  const int total0 = BATCH * 3 * npts;
  gather_kernel<<<(out_size + 255) / 256, 256, 0, stream>>>(
      x, y, sel, out, npts, total0, out_size);
}